// Round 1
// baseline (15542.439 us; speedup 1.0000x reference)
//
#include <hip/hip_runtime.h>
#include <cstdint>
#include <cstddef>

// ============================================================================
// VQ-VAE encode: conv3x3(SAME) -> linear (folded into conv) -> argmin over
// 8192 codes of |e|^2 - 2 x.e  (|x|^2 is per-row constant, dropped).
//
// Round 1: all-fp32 correctness baseline.
//   K_t   : transpose conv_w -> cwT[e][co], lin_w -> lwT[co][d]
//   K_fold: W2T[e][d] = sum_co lin_w[d,co] * conv_w[co,e]   (e = ci*9+ky*3+kx)
//   K_bias: b2[d] = sum_co lin_w[d,co]*conv_b[co] + lin_b[d]
//   K_esq : embsq[k] = |emb_k|^2
//   K_conv: y[m][d] = b2[d] + conv(latent, W2T)   m = b*64 + h*8 + w
//   K_dist: per (64-row x 256-code) tile: scores s = embsq - 2*dot, per-row
//           tile-argmin -> partials ps/pi [16384][32]
//   K_fin : merge 32 tile partials per row -> int32 index
// argmin tie-break: strict < scanning ascending k == numpy first-occurrence.
// ============================================================================

#define CIN_  512
#define E_    4608   // CIN*9
#define M_    16384  // B*H*W

// ---------------- transpose: src[R][C] -> dst[C][R] ----------------
__global__ void tkern(const float* __restrict__ src, float* __restrict__ dst,
                      int R, int C) {
    __shared__ float t[32][33];
    int c = blockIdx.x * 32 + threadIdx.x;
    int r = blockIdx.y * 32 + threadIdx.y;
    if (r < R && c < C) t[threadIdx.y][threadIdx.x] = src[(size_t)r * C + c];
    __syncthreads();
    int rr = blockIdx.x * 32 + threadIdx.y;   // dst row (old col)
    int cc = blockIdx.y * 32 + threadIdx.x;   // dst col (old row)
    if (rr < C && cc < R) dst[(size_t)rr * R + cc] = t[threadIdx.x][threadIdx.y];
}

// ---------------- fold linear into conv weights ----------------
__global__ void fold_k(const float* __restrict__ cwT, const float* __restrict__ lwT,
                       float* __restrict__ W2T) {
    int e = blockIdx.x, d = threadIdx.x;
    __shared__ float cw[256];
    cw[d] = cwT[(size_t)e * 256 + d];
    __syncthreads();
    float acc = 0.f;
    #pragma unroll 8
    for (int co = 0; co < 256; ++co) acc += cw[co] * lwT[co * 256 + d];
    W2T[(size_t)e * 256 + d] = acc;
}

__global__ void bias_k(const float* __restrict__ lwT, const float* __restrict__ conv_b,
                       const float* __restrict__ lin_b, float* __restrict__ b2) {
    int d = threadIdx.x;
    float acc = lin_b[d];
    for (int co = 0; co < 256; ++co) acc += lwT[co * 256 + d] * conv_b[co];
    b2[d] = acc;
}

// ---------------- |e_k|^2 ----------------
__global__ void embsq_k(const float* __restrict__ emb, float* __restrict__ esq) {
    int w = threadIdx.x >> 6, lane = threadIdx.x & 63;
    int k = blockIdx.x * 4 + w;
    const float* row = emb + (size_t)k * 256;
    float s = 0.f;
    #pragma unroll
    for (int i = 0; i < 4; ++i) { float v = row[lane + 64 * i]; s += v * v; }
    #pragma unroll
    for (int m = 32; m >= 1; m >>= 1) s += __shfl_xor(s, m, 64);
    if (lane == 0) esq[k] = s;
}

// ---------------- folded conv: y[m][d] ----------------
// 256 blocks (one per batch b), 512 threads: dg = d-group (32 x 8d),
// rg = row-group (16 x 4 rows). 4-ci chunks: stage lat (4x64) + W2T (36x256) in LDS.
__global__ __launch_bounds__(512) void conv_k(
    const float* __restrict__ lat, const float* __restrict__ W2T,
    const float* __restrict__ b2, float* __restrict__ y) {
    int b = blockIdx.x;
    int tid = threadIdx.x;
    int dg = tid & 31, rg = tid >> 5;
    __shared__ float lw[36 * 256];   // 36.9 KB
    __shared__ float lt[4 * 64];     // 1 KB
    float acc[4][8];
    #pragma unroll
    for (int j = 0; j < 4; ++j)
        #pragma unroll
        for (int q = 0; q < 8; ++q) acc[j][q] = 0.f;
    int hr[4], wr[4];
    #pragma unroll
    for (int j = 0; j < 4; ++j) { int r = rg * 4 + j; hr[j] = r >> 3; wr[j] = r & 7; }
    const float* latb = lat + (size_t)b * CIN_ * 64;

    for (int cc = 0; cc < 128; ++cc) {   // chunks of 4 input channels
        __syncthreads();
        if (tid < 64)
            *(float4*)&lt[tid * 4] = *(const float4*)(latb + (size_t)cc * 256 + tid * 4);
        const float4* wsrc = (const float4*)(W2T + (size_t)cc * 36 * 256);
        #pragma unroll
        for (int it = 0; it < 5; ++it) {
            int idx = tid + it * 512;           // 2304 float4 total
            if (idx < 2304) ((float4*)lw)[idx] = wsrc[idx];
        }
        __syncthreads();
        #pragma unroll
        for (int i = 0; i < 4; ++i) {
            const float* lrow = lt + i * 64;
            #pragma unroll
            for (int t9 = 0; t9 < 9; ++t9) {
                const int ky = t9 / 3, kx = t9 % 3;
                const float* wp = lw + (i * 9 + t9) * 256 + dg * 8;
                float4 w0 = *(const float4*)wp;
                float4 w1 = *(const float4*)(wp + 4);
                #pragma unroll
                for (int j = 0; j < 4; ++j) {
                    int hh = hr[j] + ky - 1, ww = wr[j] + kx - 1;
                    bool ok = ((unsigned)hh < 8u) && ((unsigned)ww < 8u);
                    float lv = ok ? lrow[(hh * 8 + ww) & 63] : 0.f;
                    acc[j][0] += lv * w0.x; acc[j][1] += lv * w0.y;
                    acc[j][2] += lv * w0.z; acc[j][3] += lv * w0.w;
                    acc[j][4] += lv * w1.x; acc[j][5] += lv * w1.y;
                    acc[j][6] += lv * w1.z; acc[j][7] += lv * w1.w;
                }
            }
        }
    }
    float4 bb0 = *(const float4*)(b2 + dg * 8);
    float4 bb1 = *(const float4*)(b2 + dg * 8 + 4);
    #pragma unroll
    for (int j = 0; j < 4; ++j) {
        int m = b * 64 + rg * 4 + j;
        float4 o0 = make_float4(acc[j][0] + bb0.x, acc[j][1] + bb0.y,
                                acc[j][2] + bb0.z, acc[j][3] + bb0.w);
        float4 o1 = make_float4(acc[j][4] + bb1.x, acc[j][5] + bb1.y,
                                acc[j][6] + bb1.z, acc[j][7] + bb1.w);
        *(float4*)(y + (size_t)m * 256 + dg * 8) = o0;
        *(float4*)(y + (size_t)m * 256 + dg * 8 + 4) = o1;
    }
}

// ---------------- distance + per-tile argmin ----------------
// grid (32 code-tiles, 256 row-tiles), 256 threads.
// Tile: 64 rows x 256 codes, K=256 in chunks of 32.
// Thread: cg = code-group (32 x 8 codes), rg = row-group (8 x 8 rows).
__global__ __launch_bounds__(256) void dist_k(
    const float* __restrict__ y, const float* __restrict__ emb,
    const float* __restrict__ esq, float* __restrict__ ps, int* __restrict__ pi) {
    int ct = blockIdx.x, rt = blockIdx.y;
    int k0 = ct * 256, m0 = rt * 64;
    int cg = threadIdx.x & 31, rg = threadIdx.x >> 5;
    __shared__ float ylds[64][32];        // 8 KB   [row][c]
    __shared__ float et[32][260];         // 33.3 KB [c][code] (+4 pad)
    float acc[8][8];
    #pragma unroll
    for (int j = 0; j < 8; ++j)
        #pragma unroll
        for (int i = 0; i < 8; ++i) acc[j][i] = 0.f;

    for (int c0 = 0; c0 < 256; c0 += 32) {
        __syncthreads();
        // stage y tile: 64 rows x 32 c
        #pragma unroll
        for (int q = 0; q < 2; ++q) {
            int ff = threadIdx.x * 8 + q * 4;
            int row = ff >> 5, c = ff & 31;
            *(float4*)&ylds[row][c] =
                *(const float4*)(y + (size_t)(m0 + row) * 256 + c0 + c);
        }
        // stage emb tile transposed: et[c][kk], 256 codes x 32 c
        {
            int kk = threadIdx.x;
            const float* er = emb + (size_t)(k0 + kk) * 256 + c0;
            #pragma unroll
            for (int q = 0; q < 8; ++q) {
                float4 v = ((const float4*)er)[q];
                et[q * 4 + 0][kk] = v.x; et[q * 4 + 1][kk] = v.y;
                et[q * 4 + 2][kk] = v.z; et[q * 4 + 3][kk] = v.w;
            }
        }
        __syncthreads();
        #pragma unroll
        for (int c4 = 0; c4 < 32; c4 += 4) {
            float4 e0[4], e1[4];
            #pragma unroll
            for (int q = 0; q < 4; ++q) {
                e0[q] = *(const float4*)&et[c4 + q][cg * 8];
                e1[q] = *(const float4*)&et[c4 + q][cg * 8 + 4];
            }
            #pragma unroll
            for (int j = 0; j < 8; ++j) {
                float4 yv = *(const float4*)&ylds[rg * 8 + j][c4];
                float ya[4] = {yv.x, yv.y, yv.z, yv.w};
                #pragma unroll
                for (int q = 0; q < 4; ++q) {
                    acc[j][0] += ya[q] * e0[q].x; acc[j][1] += ya[q] * e0[q].y;
                    acc[j][2] += ya[q] * e0[q].z; acc[j][3] += ya[q] * e0[q].w;
                    acc[j][4] += ya[q] * e1[q].x; acc[j][5] += ya[q] * e1[q].y;
                    acc[j][6] += ya[q] * e1[q].z; acc[j][7] += ya[q] * e1[q].w;
                }
            }
        }
    }
    // scores + per-row tile argmin (ascending k, strict < => first occurrence)
    float4 q0 = *(const float4*)(esq + k0 + cg * 8);
    float4 q1 = *(const float4*)(esq + k0 + cg * 8 + 4);
    float es[8] = {q0.x, q0.y, q0.z, q0.w, q1.x, q1.y, q1.z, q1.w};
    #pragma unroll
    for (int j = 0; j < 8; ++j) {
        float best = 3.4e38f; int bidx = 0;
        #pragma unroll
        for (int i = 0; i < 8; ++i) {
            float s = es[i] - 2.f * acc[j][i];
            if (s < best) { best = s; bidx = k0 + cg * 8 + i; }
        }
        #pragma unroll
        for (int mask = 1; mask <= 16; mask <<= 1) {
            float so = __shfl_xor(best, mask, 64);
            int ko = __shfl_xor(bidx, mask, 64);
            if (so < best || (so == best && ko < bidx)) { best = so; bidx = ko; }
        }
        if (cg == 0) {
            int m = m0 + rg * 8 + j;
            ps[(size_t)m * 32 + ct] = best;
            pi[(size_t)m * 32 + ct] = bidx;
        }
    }
}

// ---------------- final merge over 32 code-tiles ----------------
__global__ void final_k(const float* __restrict__ ps, const int* __restrict__ pi,
                        int* __restrict__ out) {
    int m = blockIdx.x * 256 + threadIdx.x;
    float bs = 3.4e38f; int bk = 0;
    for (int t = 0; t < 32; ++t) {
        float s = ps[(size_t)m * 32 + t];
        int k = pi[(size_t)m * 32 + t];
        if (s < bs) { bs = s; bk = k; }   // tiles ascending k; strict < keeps first
    }
    out[m] = bk;
}

extern "C" void kernel_launch(void* const* d_in, const int* in_sizes, int n_in,
                              void* d_out, int out_size, void* d_ws, size_t ws_size,
                              hipStream_t stream) {
    const float* latent = (const float*)d_in[0];   // [256,512,8,8]
    const float* conv_w = (const float*)d_in[1];   // [256,512,3,3]
    const float* conv_b = (const float*)d_in[2];   // [256]
    const float* lin_w  = (const float*)d_in[3];   // [256,256]
    const float* lin_b  = (const float*)d_in[4];   // [256]
    const float* emb    = (const float*)d_in[5];   // [8192,256]
    int* out = (int*)d_out;                        // [16384] int32

    float* ws  = (float*)d_ws;
    float* cwT = ws;                         // 4608*256
    float* lwT = cwT + (size_t)E_ * 256;     // 256*256
    float* W2T = lwT + 65536;                // 4608*256
    float* b2  = W2T + (size_t)E_ * 256;     // 256
    float* esq = b2 + 256;                   // 8192
    float* yb  = esq + 8192;                 // 16384*256
    float* ps  = yb + (size_t)M_ * 256;      // 16384*32
    int*   pi  = (int*)(ps + (size_t)M_ * 32); // 16384*32
    // total ws use: ~30.7 MB

    dim3 t32(32, 32);
    tkern<<<dim3(144, 8), t32, 0, stream>>>(conv_w, cwT, 256, E_);
    tkern<<<dim3(8, 8),   t32, 0, stream>>>(lin_w,  lwT, 256, 256);
    fold_k<<<E_, 256, 0, stream>>>(cwT, lwT, W2T);
    bias_k<<<1, 256, 0, stream>>>(lwT, conv_b, lin_b, b2);
    embsq_k<<<2048, 256, 0, stream>>>(emb, esq);
    conv_k<<<256, 512, 0, stream>>>(latent, W2T, b2, yb);
    dist_k<<<dim3(32, 256), 256, 0, stream>>>(yb, emb, esq, ps, pi);
    final_k<<<64, 256, 0, stream>>>(ps, pi, out);
}

// Round 2
// 2153.282 us; speedup vs baseline: 7.2180x; 7.2180x over previous
//
#include <hip/hip_runtime.h>
#include <cstdint>
#include <cstddef>

// ============================================================================
// VQ-VAE encode: conv3x3(SAME) -> linear (folded into conv) -> argmin over
// 8192 codes of |e|^2 - 2 x.e.
//
// Round 2: fp32, structural fixes.
//   conv_k: implicit GEMM. LDS: W-chunk [36e][256d] + im2col frag at[36e][64row].
//           Thread tile 8 rows x 8 d, d-ownership {4dg..4dg+3, 128+4dg..+3}
//           -> weight reads lane-contiguous (conflict-free), A-reads broadcast.
//           No big unrolled live set -> no scratch spill (R1: 24 GB spill traffic).
//   dist_k: code ownership {4cg, 128+4cg} -> et float4 reads lane-contiguous.
//           ylds staging writes contiguous.
// argmin tie-break: ascending k scan, strict < == numpy first-occurrence.
// ============================================================================

#define CIN_  512
#define E_    4608   // CIN*9
#define M_    16384  // B*H*W

// ---------------- transpose: src[R][C] -> dst[C][R] ----------------
__global__ void tkern(const float* __restrict__ src, float* __restrict__ dst,
                      int R, int C) {
    __shared__ float t[32][33];
    int c = blockIdx.x * 32 + threadIdx.x;
    int r = blockIdx.y * 32 + threadIdx.y;
    if (r < R && c < C) t[threadIdx.y][threadIdx.x] = src[(size_t)r * C + c];
    __syncthreads();
    int rr = blockIdx.x * 32 + threadIdx.y;
    int cc = blockIdx.y * 32 + threadIdx.x;
    if (rr < C && cc < R) dst[(size_t)rr * R + cc] = t[threadIdx.x][threadIdx.y];
}

// ---------------- fold linear into conv weights ----------------
__global__ void fold_k(const float* __restrict__ cwT, const float* __restrict__ lwT,
                       float* __restrict__ W2T) {
    int e = blockIdx.x, d = threadIdx.x;
    __shared__ float cw[256];
    cw[d] = cwT[(size_t)e * 256 + d];
    __syncthreads();
    float acc = 0.f;
    #pragma unroll 8
    for (int co = 0; co < 256; ++co) acc += cw[co] * lwT[co * 256 + d];
    W2T[(size_t)e * 256 + d] = acc;
}

__global__ void bias_k(const float* __restrict__ lwT, const float* __restrict__ conv_b,
                       const float* __restrict__ lin_b, float* __restrict__ b2) {
    int d = threadIdx.x;
    float acc = lin_b[d];
    for (int co = 0; co < 256; ++co) acc += lwT[co * 256 + d] * conv_b[co];
    b2[d] = acc;
}

// ---------------- |e_k|^2 ----------------
__global__ void embsq_k(const float* __restrict__ emb, float* __restrict__ esq) {
    int w = threadIdx.x >> 6, lane = threadIdx.x & 63;
    int k = blockIdx.x * 4 + w;
    const float* row = emb + (size_t)k * 256;
    float s = 0.f;
    #pragma unroll
    for (int i = 0; i < 4; ++i) { float v = row[lane + 64 * i]; s += v * v; }
    #pragma unroll
    for (int m = 32; m >= 1; m >>= 1) s += __shfl_xor(s, m, 64);
    if (lane == 0) esq[k] = s;
}

// ---------------- folded conv as implicit GEMM ----------------
// grid 256 (one batch b per block), 256 threads.
// dg = tid&31: owns d in {4dg..4dg+3} u {128+4dg..128+4dg+3}
// rg = tid>>5: owns rows rg*8..rg*8+7        acc[8 rows][8 d]
// K-loop: 128 chunks of 4 input channels (e-chunk of 36).
__global__ __launch_bounds__(256) void conv_k(
    const float* __restrict__ lat, const float* __restrict__ W2T,
    const float* __restrict__ b2, float* __restrict__ y) {
    int b = blockIdx.x;
    int tid = threadIdx.x;
    int dg = tid & 31, rg = tid >> 5;
    __shared__ float lw[36 * 256];   // [e][d]      36.9 KB
    __shared__ float at[36 * 72];    // [e][row+8]  10.4 KB
    float acc[8][8];
    #pragma unroll
    for (int j = 0; j < 8; ++j)
        #pragma unroll
        for (int i = 0; i < 8; ++i) acc[j][i] = 0.f;
    const float* latb = lat + (size_t)b * CIN_ * 64;

    for (int cc = 0; cc < 128; ++cc) {
        __syncthreads();
        // stage weights: 36*256 floats = 2304 float4, 9 per thread (contiguous)
        const float4* wsrc = (const float4*)(W2T + (size_t)cc * 36 * 256);
        float4* wdst = (float4*)lw;
        #pragma unroll
        for (int i = 0; i < 9; ++i) wdst[tid + i * 256] = wsrc[tid + i * 256];
        // build im2col fragment: 36*64 entries, 9 per thread
        #pragma unroll
        for (int i = 0; i < 9; ++i) {
            int n = tid + i * 256;
            int e = n >> 6, row = n & 63;
            int ci4 = (e * 456) >> 12;          // e/9 for e<36
            int t9 = e - ci4 * 9;
            int dy = (t9 * 342) >> 10;          // t9/3
            int dx = t9 - dy * 3;
            int hh = (row >> 3) + dy - 1, ww = (row & 7) + dx - 1;
            float v = 0.f;
            if (((unsigned)hh < 8u) && ((unsigned)ww < 8u))
                v = latb[(size_t)(cc * 4 + ci4) * 64 + hh * 8 + ww];
            at[e * 72 + row] = v;
        }
        __syncthreads();
        // compute: 9 e-quads
        #pragma unroll 3
        for (int e4 = 0; e4 < 36; e4 += 4) {
            float4 a0[4], a1[4], w0[4], w1[4];
            #pragma unroll
            for (int q = 0; q < 4; ++q) {
                const float* ap = &at[(e4 + q) * 72 + rg * 8];
                a0[q] = *(const float4*)ap;
                a1[q] = *(const float4*)(ap + 4);
                const float* wp = &lw[(e4 + q) * 256 + dg * 4];
                w0[q] = *(const float4*)wp;
                w1[q] = *(const float4*)(wp + 128);
            }
            #pragma unroll
            for (int q = 0; q < 4; ++q) {
                float aj[8] = {a0[q].x, a0[q].y, a0[q].z, a0[q].w,
                               a1[q].x, a1[q].y, a1[q].z, a1[q].w};
                float wd[8] = {w0[q].x, w0[q].y, w0[q].z, w0[q].w,
                               w1[q].x, w1[q].y, w1[q].z, w1[q].w};
                #pragma unroll
                for (int j = 0; j < 8; ++j)
                    #pragma unroll
                    for (int i = 0; i < 8; ++i)
                        acc[j][i] += aj[j] * wd[i];
            }
        }
    }
    // epilogue: + bias, store (coalesced: 4dg contiguous across dg)
    float4 bb0 = *(const float4*)(b2 + dg * 4);
    float4 bb1 = *(const float4*)(b2 + 128 + dg * 4);
    #pragma unroll
    for (int j = 0; j < 8; ++j) {
        int m = b * 64 + rg * 8 + j;
        float4 o0 = make_float4(acc[j][0] + bb0.x, acc[j][1] + bb0.y,
                                acc[j][2] + bb0.z, acc[j][3] + bb0.w);
        float4 o1 = make_float4(acc[j][4] + bb1.x, acc[j][5] + bb1.y,
                                acc[j][6] + bb1.z, acc[j][7] + bb1.w);
        *(float4*)(y + (size_t)m * 256 + dg * 4) = o0;
        *(float4*)(y + (size_t)m * 256 + 128 + dg * 4) = o1;
    }
}

// ---------------- distance + per-tile argmin ----------------
// grid (32 code-tiles, 256 row-tiles), 256 threads. Tile: 64 rows x 256 codes.
// cg = tid&31: owns codes {4cg..4cg+3} u {128+4cg..+3}  (et reads contiguous)
// rg = tid>>5: owns rows rg*8..rg*8+7
__global__ __launch_bounds__(256) void dist_k(
    const float* __restrict__ y, const float* __restrict__ emb,
    const float* __restrict__ esq, float* __restrict__ ps, int* __restrict__ pi) {
    int ct = blockIdx.x, rt = blockIdx.y;
    int k0 = ct * 256, m0 = rt * 64;
    int cg = threadIdx.x & 31, rg = threadIdx.x >> 5;
    __shared__ float ylds[64][32];        // 8 KB   [row][c]
    __shared__ float et[32][260];         // 33.3 KB [c][code]
    float acc[8][8];
    #pragma unroll
    for (int j = 0; j < 8; ++j)
        #pragma unroll
        for (int i = 0; i < 8; ++i) acc[j][i] = 0.f;

    for (int c0 = 0; c0 < 256; c0 += 32) {
        __syncthreads();
        // stage y tile (contiguous LDS writes: lane t -> float4 slot t)
        #pragma unroll
        for (int i = 0; i < 2; ++i) {
            int f = i * 1024 + threadIdx.x * 4;
            int row = f >> 5, c = f & 31;
            *(float4*)&ylds[row][c] =
                *(const float4*)(y + (size_t)(m0 + row) * 256 + c0 + c);
        }
        // stage emb tile transposed: et[c][kk]
        {
            int kk = threadIdx.x;
            const float* er = emb + (size_t)(k0 + kk) * 256 + c0;
            #pragma unroll
            for (int q = 0; q < 8; ++q) {
                float4 v = ((const float4*)er)[q];
                et[q * 4 + 0][kk] = v.x; et[q * 4 + 1][kk] = v.y;
                et[q * 4 + 2][kk] = v.z; et[q * 4 + 3][kk] = v.w;
            }
        }
        __syncthreads();
        #pragma unroll
        for (int c4 = 0; c4 < 32; c4 += 4) {
            float4 e0[4], e1[4];
            #pragma unroll
            for (int q = 0; q < 4; ++q) {
                e0[q] = *(const float4*)&et[c4 + q][cg * 4];         // codes 4cg..
                e1[q] = *(const float4*)&et[c4 + q][128 + cg * 4];   // codes 128+4cg..
            }
            #pragma unroll
            for (int j = 0; j < 8; ++j) {
                float4 yv = *(const float4*)&ylds[rg * 8 + j][c4];
                float ya[4] = {yv.x, yv.y, yv.z, yv.w};
                #pragma unroll
                for (int q = 0; q < 4; ++q) {
                    acc[j][0] += ya[q] * e0[q].x; acc[j][1] += ya[q] * e0[q].y;
                    acc[j][2] += ya[q] * e0[q].z; acc[j][3] += ya[q] * e0[q].w;
                    acc[j][4] += ya[q] * e1[q].x; acc[j][5] += ya[q] * e1[q].y;
                    acc[j][6] += ya[q] * e1[q].z; acc[j][7] += ya[q] * e1[q].w;
                }
            }
        }
    }
    // scores + per-row tile argmin (ascending k within thread; strict <)
    float4 q0 = *(const float4*)(esq + k0 + cg * 4);
    float4 q1 = *(const float4*)(esq + k0 + 128 + cg * 4);
    float es[8] = {q0.x, q0.y, q0.z, q0.w, q1.x, q1.y, q1.z, q1.w};
    #pragma unroll
    for (int j = 0; j < 8; ++j) {
        float best = 3.4e38f; int bidx = 0;
        #pragma unroll
        for (int i = 0; i < 8; ++i) {
            float s = es[i] - 2.f * acc[j][i];
            int k = (i < 4) ? (k0 + 4 * cg + i) : (k0 + 128 + 4 * cg + (i - 4));
            if (s < best) { best = s; bidx = k; }
        }
        #pragma unroll
        for (int mask = 1; mask <= 16; mask <<= 1) {
            float so = __shfl_xor(best, mask, 64);
            int ko = __shfl_xor(bidx, mask, 64);
            if (so < best || (so == best && ko < bidx)) { best = so; bidx = ko; }
        }
        if (cg == 0) {
            int m = m0 + rg * 8 + j;
            ps[(size_t)m * 32 + ct] = best;
            pi[(size_t)m * 32 + ct] = bidx;
        }
    }
}

// ---------------- final merge over 32 code-tiles ----------------
__global__ void final_k(const float* __restrict__ ps, const int* __restrict__ pi,
                        int* __restrict__ out) {
    int m = blockIdx.x * 256 + threadIdx.x;
    float bs = 3.4e38f; int bk = 0;
    for (int t = 0; t < 32; ++t) {
        float s = ps[(size_t)m * 32 + t];
        int k = pi[(size_t)m * 32 + t];
        if (s < bs) { bs = s; bk = k; }   // tiles ascending k; strict < keeps first
    }
    out[m] = bk;
}

extern "C" void kernel_launch(void* const* d_in, const int* in_sizes, int n_in,
                              void* d_out, int out_size, void* d_ws, size_t ws_size,
                              hipStream_t stream) {
    const float* latent = (const float*)d_in[0];   // [256,512,8,8]
    const float* conv_w = (const float*)d_in[1];   // [256,512,3,3]
    const float* conv_b = (const float*)d_in[2];   // [256]
    const float* lin_w  = (const float*)d_in[3];   // [256,256]
    const float* lin_b  = (const float*)d_in[4];   // [256]
    const float* emb    = (const float*)d_in[5];   // [8192,256]
    int* out = (int*)d_out;                        // [16384] int32

    float* ws  = (float*)d_ws;
    float* cwT = ws;                           // 4608*256
    float* lwT = cwT + (size_t)E_ * 256;       // 256*256
    float* W2T = lwT + 65536;                  // 4608*256
    float* b2  = W2T + (size_t)E_ * 256;       // 256
    float* esq = b2 + 256;                     // 8192
    float* yb  = esq + 8192;                   // 16384*256
    float* ps  = yb + (size_t)M_ * 256;        // 16384*32
    int*   pi  = (int*)(ps + (size_t)M_ * 32); // 16384*32

    dim3 t32(32, 32);
    tkern<<<dim3(144, 8), t32, 0, stream>>>(conv_w, cwT, 256, E_);
    tkern<<<dim3(8, 8),   t32, 0, stream>>>(lin_w,  lwT, 256, 256);
    fold_k<<<E_, 256, 0, stream>>>(cwT, lwT, W2T);
    bias_k<<<1, 256, 0, stream>>>(lwT, conv_b, lin_b, b2);
    embsq_k<<<2048, 256, 0, stream>>>(emb, esq);
    conv_k<<<256, 256, 0, stream>>>(latent, W2T, b2, yb);
    dist_k<<<dim3(32, 256), 256, 0, stream>>>(yb, emb, esq, ps, pi);
    final_k<<<64, 256, 0, stream>>>(ps, pi, out);
}

// Round 3
// 1160.089 us; speedup vs baseline: 13.3976x; 1.8561x over previous
//
#include <hip/hip_runtime.h>
#include <cstdint>
#include <cstddef>

// ============================================================================
// VQ-VAE encode: conv3x3(SAME) -> linear (folded into conv) -> argmin over
// 8192 codes of |e|^2 - 2 x.e.
//
// Round 3: distance matmul moved to matrix cores.
//   pack:   y -> [yh|yl] fp16 (hi = fp16(x), lo = fp16(x-hi)); emb -> [eh|el].
//   screen: fp16 MFMA GEMM, effective K=768 (yh.eh + yh.el + yl.eh via
//           segment-remapped K-loop). m97 structure: 128x128 tile, 4 waves,
//           16x16x32 f16, global_load_lds width=16. Fused epilogue: score =
//           esq - 2*dot, per-row argmin per 64-code group -> 128 cand/row.
//   refine: exact fp32 re-score of candidates within delta of screen min.
//           Screen err ~1e-4 << delta=0.05 << typical win gap ~20.
// argmin tie-break everywhere: strict < with smaller-index preference.
// Fallback: if ws_size < fast-path need, use round-2 fp32 dist path.
// ============================================================================

#define CIN_  512
#define E_    4608   // CIN*9
#define M_    16384  // B*H*W

typedef _Float16 half4_t __attribute__((ext_vector_type(4)));
typedef _Float16 half8_t __attribute__((ext_vector_type(8)));
typedef float f32x4 __attribute__((ext_vector_type(4)));

#define GLOAD_LDS16(gptr, lptr)                                         \
    __builtin_amdgcn_global_load_lds(                                   \
        (const __attribute__((address_space(1))) unsigned int*)(gptr),  \
        (__attribute__((address_space(3))) unsigned int*)(lptr), 16, 0, 0)

// ---------------- transpose: src[R][C] -> dst[C][R] ----------------
__global__ void tkern(const float* __restrict__ src, float* __restrict__ dst,
                      int R, int C) {
    __shared__ float t[32][33];
    int c = blockIdx.x * 32 + threadIdx.x;
    int r = blockIdx.y * 32 + threadIdx.y;
    if (r < R && c < C) t[threadIdx.y][threadIdx.x] = src[(size_t)r * C + c];
    __syncthreads();
    int rr = blockIdx.x * 32 + threadIdx.y;
    int cc = blockIdx.y * 32 + threadIdx.x;
    if (rr < C && cc < R) dst[(size_t)rr * R + cc] = t[threadIdx.x][threadIdx.y];
}

// ---------------- fold linear into conv weights (gathers conv_w column) -----
__global__ void fold2_k(const float* __restrict__ conv_w, const float* __restrict__ lwT,
                        float* __restrict__ W2T) {
    int e = blockIdx.x, d = threadIdx.x;
    __shared__ float cw[256];
    cw[d] = conv_w[(size_t)d * E_ + e];      // conv_w[co=d][e]
    __syncthreads();
    float acc = 0.f;
    #pragma unroll 8
    for (int co = 0; co < 256; ++co) acc += cw[co] * lwT[co * 256 + d];
    W2T[(size_t)e * 256 + d] = acc;
}

__global__ void bias_k(const float* __restrict__ lwT, const float* __restrict__ conv_b,
                       const float* __restrict__ lin_b, float* __restrict__ b2) {
    int d = threadIdx.x;
    float acc = lin_b[d];
    for (int co = 0; co < 256; ++co) acc += lwT[co * 256 + d] * conv_b[co];
    b2[d] = acc;
}

// ---------------- |e_k|^2 ----------------
__global__ void embsq_k(const float* __restrict__ emb, float* __restrict__ esq) {
    int w = threadIdx.x >> 6, lane = threadIdx.x & 63;
    int k = blockIdx.x * 4 + w;
    const float* row = emb + (size_t)k * 256;
    float s = 0.f;
    #pragma unroll
    for (int i = 0; i < 4; ++i) { float v = row[lane + 64 * i]; s += v * v; }
    #pragma unroll
    for (int m = 32; m >= 1; m >>= 1) s += __shfl_xor(s, m, 64);
    if (lane == 0) esq[k] = s;
}

// ---------------- folded conv as implicit GEMM (round-2, verified) ----------
__global__ __launch_bounds__(256) void conv_k(
    const float* __restrict__ lat, const float* __restrict__ W2T,
    const float* __restrict__ b2, float* __restrict__ y) {
    int b = blockIdx.x;
    int tid = threadIdx.x;
    int dg = tid & 31, rg = tid >> 5;
    __shared__ float lw[36 * 256];
    __shared__ float at[36 * 72];
    float acc[8][8];
    #pragma unroll
    for (int j = 0; j < 8; ++j)
        #pragma unroll
        for (int i = 0; i < 8; ++i) acc[j][i] = 0.f;
    const float* latb = lat + (size_t)b * CIN_ * 64;

    for (int cc = 0; cc < 128; ++cc) {
        __syncthreads();
        const float4* wsrc = (const float4*)(W2T + (size_t)cc * 36 * 256);
        float4* wdst = (float4*)lw;
        #pragma unroll
        for (int i = 0; i < 9; ++i) wdst[tid + i * 256] = wsrc[tid + i * 256];
        #pragma unroll
        for (int i = 0; i < 9; ++i) {
            int n = tid + i * 256;
            int e = n >> 6, row = n & 63;
            int ci4 = (e * 456) >> 12;
            int t9 = e - ci4 * 9;
            int dy = (t9 * 342) >> 10;
            int dx = t9 - dy * 3;
            int hh = (row >> 3) + dy - 1, ww = (row & 7) + dx - 1;
            float v = 0.f;
            if (((unsigned)hh < 8u) && ((unsigned)ww < 8u))
                v = latb[(size_t)(cc * 4 + ci4) * 64 + hh * 8 + ww];
            at[e * 72 + row] = v;
        }
        __syncthreads();
        #pragma unroll 3
        for (int e4 = 0; e4 < 36; e4 += 4) {
            float4 a0[4], a1[4], w0[4], w1[4];
            #pragma unroll
            for (int q = 0; q < 4; ++q) {
                const float* ap = &at[(e4 + q) * 72 + rg * 8];
                a0[q] = *(const float4*)ap;
                a1[q] = *(const float4*)(ap + 4);
                const float* wp = &lw[(e4 + q) * 256 + dg * 4];
                w0[q] = *(const float4*)wp;
                w1[q] = *(const float4*)(wp + 128);
            }
            #pragma unroll
            for (int q = 0; q < 4; ++q) {
                float aj[8] = {a0[q].x, a0[q].y, a0[q].z, a0[q].w,
                               a1[q].x, a1[q].y, a1[q].z, a1[q].w};
                float wd[8] = {w0[q].x, w0[q].y, w0[q].z, w0[q].w,
                               w1[q].x, w1[q].y, w1[q].z, w1[q].w};
                #pragma unroll
                for (int j = 0; j < 8; ++j)
                    #pragma unroll
                    for (int i = 0; i < 8; ++i)
                        acc[j][i] += aj[j] * wd[i];
            }
        }
    }
    float4 bb0 = *(const float4*)(b2 + dg * 4);
    float4 bb1 = *(const float4*)(b2 + 128 + dg * 4);
    #pragma unroll
    for (int j = 0; j < 8; ++j) {
        int m = b * 64 + rg * 8 + j;
        float4 o0 = make_float4(acc[j][0] + bb0.x, acc[j][1] + bb0.y,
                                acc[j][2] + bb0.z, acc[j][3] + bb0.w);
        float4 o1 = make_float4(acc[j][4] + bb1.x, acc[j][5] + bb1.y,
                                acc[j][6] + bb1.z, acc[j][7] + bb1.w);
        *(float4*)(y + (size_t)m * 256 + dg * 4) = o0;
        *(float4*)(y + (size_t)m * 256 + 128 + dg * 4) = o1;
    }
}

// ---------------- hi/lo fp16 split pack: x[rows][256] -> o[rows][512] -------
__global__ void pack_k(const float* __restrict__ x, _Float16* __restrict__ o) {
    int i = blockIdx.x * 256 + threadIdx.x;     // one float4 per thread
    int m = i >> 6, c = (i & 63) * 4;
    float4 v = *(const float4*)(x + (size_t)m * 256 + c);
    float vf[4] = {v.x, v.y, v.z, v.w};
    half4_t hh, ll;
    #pragma unroll
    for (int q = 0; q < 4; ++q) {
        _Float16 h = (_Float16)vf[q];
        hh[q] = h;
        ll[q] = (_Float16)(vf[q] - (float)h);
    }
    *(half4_t*)(o + (size_t)m * 512 + c) = hh;
    *(half4_t*)(o + (size_t)m * 512 + 256 + c) = ll;
}

// ---------------- MFMA screen: scores + per-64-code-group argmin ------------
// grid (128 m-tiles, 64 n-tiles), 256 threads = 4 waves (2x2 of 64x64).
// K-loop kt=0..23 maps to segments: A cols {yh,yh,yl}, B cols {eh,el,eh}.
__global__ __launch_bounds__(256) void screen_k(
    const _Float16* __restrict__ A2, const _Float16* __restrict__ B2,
    const float* __restrict__ esq, float* __restrict__ ps2, int* __restrict__ pi2) {
    int m0 = blockIdx.x * 128, n0 = blockIdx.y * 128;
    int tid = threadIdx.x, w = tid >> 6, lane = tid & 63;
    int wm = w & 1, wn = w >> 1;
    int fr = lane & 15, fq = lane >> 4;
    __shared__ _Float16 la[128 * 32];
    __shared__ _Float16 lb[128 * 32];
    f32x4 acc[4][4];
    #pragma unroll
    for (int s = 0; s < 4; ++s)
        #pragma unroll
        for (int t = 0; t < 4; ++t)
            #pragma unroll
            for (int r = 0; r < 4; ++r) acc[s][t][r] = 0.f;

    // per-lane staging geometry: lds byte off = w*2048 + i*1024 + lane*16
    int off0 = w * 2048 + lane * 16;
    int row0 = off0 >> 6, cb0 = (off0 & 63) >> 1;        // i=0
    int off1 = off0 + 1024;
    int row1 = off1 >> 6, cb1 = (off1 & 63) >> 1;        // i=1

    for (int kt = 0; kt < 24; ++kt) {
        int seg = kt >> 3;
        int akoff = ((kt & 7) << 5) + (seg == 2 ? 256 : 0);   // yh,yh,yl
        int bkoff = ((kt & 7) << 5) + (seg == 1 ? 256 : 0);   // eh,el,eh
        __syncthreads();
        GLOAD_LDS16(A2 + (size_t)(m0 + row0) * 512 + akoff + cb0,
                    (char*)la + (w * 2048));
        GLOAD_LDS16(A2 + (size_t)(m0 + row1) * 512 + akoff + cb1,
                    (char*)la + (w * 2048 + 1024));
        GLOAD_LDS16(B2 + (size_t)(n0 + row0) * 512 + bkoff + cb0,
                    (char*)lb + (w * 2048));
        GLOAD_LDS16(B2 + (size_t)(n0 + row1) * 512 + bkoff + cb1,
                    (char*)lb + (w * 2048 + 1024));
        __syncthreads();
        half8_t af[4], bf[4];
        #pragma unroll
        for (int s = 0; s < 4; ++s)
            af[s] = *(const half8_t*)&la[(wm * 64 + s * 16 + fr) * 32 + fq * 8];
        #pragma unroll
        for (int t = 0; t < 4; ++t)
            bf[t] = *(const half8_t*)&lb[(wn * 64 + t * 16 + fr) * 32 + fq * 8];
        #pragma unroll
        for (int s = 0; s < 4; ++s)
            #pragma unroll
            for (int t = 0; t < 4; ++t)
                acc[s][t] = __builtin_amdgcn_mfma_f32_16x16x32_f16(
                    af[s], bf[t], acc[s][t], 0, 0, 0);
    }

    // epilogue: score = esq - 2*dot; per-row argmin over this wave's 64 codes.
    // C/D layout: row = fq*4 + r, col = fr  (within each 16x16 tile).
    float esv[4];
    #pragma unroll
    for (int t = 0; t < 4; ++t) esv[t] = esq[n0 + wn * 64 + t * 16 + fr];
    int colIdx = blockIdx.y * 2 + wn;    // 0..127 candidate slot
    #pragma unroll
    for (int s = 0; s < 4; ++s) {
        #pragma unroll
        for (int r = 0; r < 4; ++r) {
            float best = 3.4e38f; int bidx = 0x7fffffff;
            #pragma unroll
            for (int t = 0; t < 4; ++t) {
                float sc = esv[t] - 2.f * acc[s][t][r];
                int k = n0 + wn * 64 + t * 16 + fr;
                if (sc < best || (sc == best && k < bidx)) { best = sc; bidx = k; }
            }
            #pragma unroll
            for (int msk = 1; msk <= 8; msk <<= 1) {
                float so = __shfl_xor(best, msk, 64);
                int ko = __shfl_xor(bidx, msk, 64);
                if (so < best || (so == best && ko < bidx)) { best = so; bidx = ko; }
            }
            if (fr == 0) {
                int m = m0 + wm * 64 + s * 16 + fq * 4 + r;
                ps2[(size_t)m * 128 + colIdx] = best;
                pi2[(size_t)m * 128 + colIdx] = bidx;
            }
        }
    }
}

// ---------------- exact fp32 refine over screen candidates ----------------
__global__ __launch_bounds__(256) void refine_k(
    const float* __restrict__ y, const float* __restrict__ emb,
    const float* __restrict__ esq, const float* __restrict__ ps2,
    const int* __restrict__ pi2, int* __restrict__ out) {
    int lane = threadIdx.x & 63;
    int m = blockIdx.x * 4 + (threadIdx.x >> 6);
    float4 yv = *(const float4*)(y + (size_t)m * 256 + lane * 4);
    float sc_[2]; int kc_[2];
    #pragma unroll
    for (int i = 0; i < 2; ++i) {
        sc_[i] = ps2[(size_t)m * 128 + lane * 2 + i];
        kc_[i] = pi2[(size_t)m * 128 + lane * 2 + i];
    }
    float s0 = fminf(sc_[0], sc_[1]);
    #pragma unroll
    for (int msk = 1; msk <= 32; msk <<= 1) s0 = fminf(s0, __shfl_xor(s0, msk, 64));
    float thr = s0 + 0.05f;
    float best = 3.4e38f; int bk = 0x7fffffff;
    for (int c = 0; c < 128; ++c) {
        float scc = __shfl(sc_[c & 1], c >> 1, 64);
        if (scc <= thr) {            // wave-uniform condition
            int k = __shfl(kc_[c & 1], c >> 1, 64);
            float4 ev = *(const float4*)(emb + (size_t)k * 256 + lane * 4);
            float d = yv.x * ev.x + yv.y * ev.y + yv.z * ev.z + yv.w * ev.w;
            #pragma unroll
            for (int msk = 1; msk <= 32; msk <<= 1) d += __shfl_xor(d, msk, 64);
            float sx = esq[k] - 2.f * d;
            if (sx < best || (sx == best && k < bk)) { best = sx; bk = k; }
        }
    }
    if (lane == 0) out[m] = bk;
}

// ---------------- round-2 fp32 dist path (fallback if ws too small) --------
__global__ __launch_bounds__(256) void dist_k(
    const float* __restrict__ y, const float* __restrict__ emb,
    const float* __restrict__ esq, float* __restrict__ ps, int* __restrict__ pi) {
    int ct = blockIdx.x, rt = blockIdx.y;
    int k0 = ct * 256, m0 = rt * 64;
    int cg = threadIdx.x & 31, rg = threadIdx.x >> 5;
    __shared__ float ylds[64][32];
    __shared__ float et[32][260];
    float acc[8][8];
    #pragma unroll
    for (int j = 0; j < 8; ++j)
        #pragma unroll
        for (int i = 0; i < 8; ++i) acc[j][i] = 0.f;
    for (int c0 = 0; c0 < 256; c0 += 32) {
        __syncthreads();
        #pragma unroll
        for (int i = 0; i < 2; ++i) {
            int f = i * 1024 + threadIdx.x * 4;
            int row = f >> 5, c = f & 31;
            *(float4*)&ylds[row][c] =
                *(const float4*)(y + (size_t)(m0 + row) * 256 + c0 + c);
        }
        {
            int kk = threadIdx.x;
            const float* er = emb + (size_t)(k0 + kk) * 256 + c0;
            #pragma unroll
            for (int q = 0; q < 8; ++q) {
                float4 v = ((const float4*)er)[q];
                et[q * 4 + 0][kk] = v.x; et[q * 4 + 1][kk] = v.y;
                et[q * 4 + 2][kk] = v.z; et[q * 4 + 3][kk] = v.w;
            }
        }
        __syncthreads();
        #pragma unroll
        for (int c4 = 0; c4 < 32; c4 += 4) {
            float4 e0[4], e1[4];
            #pragma unroll
            for (int q = 0; q < 4; ++q) {
                e0[q] = *(const float4*)&et[c4 + q][cg * 4];
                e1[q] = *(const float4*)&et[c4 + q][128 + cg * 4];
            }
            #pragma unroll
            for (int j = 0; j < 8; ++j) {
                float4 yv = *(const float4*)&ylds[rg * 8 + j][c4];
                float ya[4] = {yv.x, yv.y, yv.z, yv.w};
                #pragma unroll
                for (int q = 0; q < 4; ++q) {
                    acc[j][0] += ya[q] * e0[q].x; acc[j][1] += ya[q] * e0[q].y;
                    acc[j][2] += ya[q] * e0[q].z; acc[j][3] += ya[q] * e0[q].w;
                    acc[j][4] += ya[q] * e1[q].x; acc[j][5] += ya[q] * e1[q].y;
                    acc[j][6] += ya[q] * e1[q].z; acc[j][7] += ya[q] * e1[q].w;
                }
            }
        }
    }
    float4 q0 = *(const float4*)(esq + k0 + cg * 4);
    float4 q1 = *(const float4*)(esq + k0 + 128 + cg * 4);
    float es[8] = {q0.x, q0.y, q0.z, q0.w, q1.x, q1.y, q1.z, q1.w};
    #pragma unroll
    for (int j = 0; j < 8; ++j) {
        float best = 3.4e38f; int bidx = 0;
        #pragma unroll
        for (int i = 0; i < 8; ++i) {
            float s = es[i] - 2.f * acc[j][i];
            int k = (i < 4) ? (k0 + 4 * cg + i) : (k0 + 128 + 4 * cg + (i - 4));
            if (s < best) { best = s; bidx = k; }
        }
        #pragma unroll
        for (int mask = 1; mask <= 16; mask <<= 1) {
            float so = __shfl_xor(best, mask, 64);
            int ko = __shfl_xor(bidx, mask, 64);
            if (so < best || (so == best && ko < bidx)) { best = so; bidx = ko; }
        }
        if (cg == 0) {
            int m = m0 + rg * 8 + j;
            ps[(size_t)m * 32 + ct] = best;
            pi[(size_t)m * 32 + ct] = bidx;
        }
    }
}

__global__ void final_k(const float* __restrict__ ps, const int* __restrict__ pi,
                        int* __restrict__ out) {
    int m = blockIdx.x * 256 + threadIdx.x;
    float bs = 3.4e38f; int bk = 0;
    for (int t = 0; t < 32; ++t) {
        float s = ps[(size_t)m * 32 + t];
        int k = pi[(size_t)m * 32 + t];
        if (s < bs) { bs = s; bk = k; }
    }
    out[m] = bk;
}

extern "C" void kernel_launch(void* const* d_in, const int* in_sizes, int n_in,
                              void* d_out, int out_size, void* d_ws, size_t ws_size,
                              hipStream_t stream) {
    const float* latent = (const float*)d_in[0];
    const float* conv_w = (const float*)d_in[1];
    const float* conv_b = (const float*)d_in[2];
    const float* lin_w  = (const float*)d_in[3];
    const float* lin_b  = (const float*)d_in[4];
    const float* emb    = (const float*)d_in[5];
    int* out = (int*)d_out;

    float* ws  = (float*)d_ws;
    float* lwT = ws;                           // 65536
    float* W2T = lwT + 65536;                  // E_*256 = 1179648
    float* b2  = W2T + (size_t)E_ * 256;       // 256
    float* esq = b2 + 256;                     // 8192
    float* yb  = esq + 8192;                   // M_*256 = 4194304
    float* ps2 = yb + (size_t)M_ * 256;        // M_*128 = 2097152
    int*   pi2 = (int*)(ps2 + (size_t)M_ * 128);
    _Float16* A2 = (_Float16*)(pi2 + (size_t)M_ * 128);  // M_*512 halves
    _Float16* B2 = A2 + (size_t)M_ * 512;                // 8192*512 halves
    size_t need_fast = ((size_t)(65536 + 1179648 + 256 + 8192 + 4194304
                        + 2097152 + 2097152)) * 4
                     + ((size_t)M_ * 512 + (size_t)8192 * 512) * 2;

    dim3 t32(32, 32);
    tkern<<<dim3(8, 8), t32, 0, stream>>>(lin_w, lwT, 256, 256);
    fold2_k<<<E_, 256, 0, stream>>>(conv_w, lwT, W2T);
    bias_k<<<1, 256, 0, stream>>>(lwT, conv_b, lin_b, b2);
    embsq_k<<<2048, 256, 0, stream>>>(emb, esq);
    conv_k<<<256, 256, 0, stream>>>(latent, W2T, b2, yb);

    if (ws_size >= need_fast) {
        pack_k<<<4096, 256, 0, stream>>>(yb, A2);    // 16384 rows
        pack_k<<<2048, 256, 0, stream>>>(emb, B2);   // 8192 rows
        screen_k<<<dim3(128, 64), 256, 0, stream>>>(A2, B2, esq, ps2, pi2);
        refine_k<<<4096, 256, 0, stream>>>(yb, emb, esq, ps2, pi2, out);
    } else {
        float* ps = ps2;                       // M_*32
        int*   pi = (int*)(ps + (size_t)M_ * 32);
        dist_k<<<dim3(32, 256), 256, 0, stream>>>(yb, emb, esq, ps, pi);
        final_k<<<64, 256, 0, stream>>>(ps, pi, out);
    }
}

// Round 4
// 592.032 us; speedup vs baseline: 26.2527x; 1.9595x over previous
//
#include <hip/hip_runtime.h>
#include <cstdint>
#include <cstddef>

// ============================================================================
// VQ-VAE encode: conv3x3(SAME) -> linear (folded into conv) -> argmin over
// 8192 codes of |e|^2 - 2 x.e.
//
// Round 4:
//   convm_k: conv as hi/lo-split fp16 MFMA GEMM (screen_k structure clone).
//     A = latent channel-last fp16 {hi,lo} planes, halo via zero-page redirect.
//     B = folded weights W2x[plane][tap][d][512c] fp16 (fold3_k writes hi/lo
//     directly from exact fp32 fold). 3 segments (AhWh, AhWl, AlWh) x 9 taps
//     x 16 c-chunks = 432 K-iters. Dropped AlWl ~ 1e-7 on y.
//   screen2_k: hi-only fp16 MFMA screen, K=256 (err sigma ~0.03), per-64-code
//     group argmin -> 128 candidates/row.
//   refine2_k: exact fp32 re-score of candidates within delta=0.25 of screen
//     min (>=8 sigma) -> numpy-exact winner.
// argmin tie-break everywhere: strict < with smaller-index preference.
// Fallback (ws too small): round-2 all-fp32 path.
// ============================================================================

#define CIN_  512
#define E_    4608   // CIN*9
#define M_    16384  // B*H*W

typedef _Float16 half4_t __attribute__((ext_vector_type(4)));
typedef _Float16 half8_t __attribute__((ext_vector_type(8)));
typedef float f32x4 __attribute__((ext_vector_type(4)));

#define GLOAD_LDS16(gptr, lptr)                                         \
    __builtin_amdgcn_global_load_lds(                                   \
        (const __attribute__((address_space(1))) unsigned int*)(gptr),  \
        (__attribute__((address_space(3))) unsigned int*)(lptr), 16, 0, 0)

// ---------------- transpose: src[R][C] -> dst[C][R] ----------------
__global__ void tkern(const float* __restrict__ src, float* __restrict__ dst,
                      int R, int C) {
    __shared__ float t[32][33];
    int c = blockIdx.x * 32 + threadIdx.x;
    int r = blockIdx.y * 32 + threadIdx.y;
    if (r < R && c < C) t[threadIdx.y][threadIdx.x] = src[(size_t)r * C + c];
    __syncthreads();
    int rr = blockIdx.x * 32 + threadIdx.y;
    int cc = blockIdx.y * 32 + threadIdx.x;
    if (rr < C && cc < R) dst[(size_t)rr * R + cc] = t[threadIdx.x][threadIdx.y];
}

// ---------------- fold linear into conv weights -> fp16 hi/lo, tap-major ----
// e = c*9 + t9. W2x[((plane*9 + t9)*256 + d)*512 + c], plane0=hi, plane1=lo.
__global__ void fold3_k(const float* __restrict__ conv_w, const float* __restrict__ lwT,
                        _Float16* __restrict__ W2x) {
    int e = blockIdx.x, d = threadIdx.x;
    __shared__ float cw[256];
    cw[d] = conv_w[(size_t)d * E_ + e];      // conv_w[co=d][e]
    __syncthreads();
    float acc = 0.f;
    #pragma unroll 8
    for (int co = 0; co < 256; ++co) acc += cw[co] * lwT[co * 256 + d];
    int c = e / 9, t9 = e - c * 9;
    _Float16 h = (_Float16)acc;
    _Float16 l = (_Float16)(acc - (float)h);
    W2x[((size_t)(t9 * 256 + d)) * 512 + c] = h;
    W2x[((size_t)((9 + t9) * 256 + d)) * 512 + c] = l;
}

// fp32 fold for fallback path
__global__ void fold2_k(const float* __restrict__ conv_w, const float* __restrict__ lwT,
                        float* __restrict__ W2T) {
    int e = blockIdx.x, d = threadIdx.x;
    __shared__ float cw[256];
    cw[d] = conv_w[(size_t)d * E_ + e];
    __syncthreads();
    float acc = 0.f;
    #pragma unroll 8
    for (int co = 0; co < 256; ++co) acc += cw[co] * lwT[co * 256 + d];
    W2T[(size_t)e * 256 + d] = acc;
}

__global__ void bias_k(const float* __restrict__ lwT, const float* __restrict__ conv_b,
                       const float* __restrict__ lin_b, float* __restrict__ b2) {
    int d = threadIdx.x;
    float acc = lin_b[d];
    for (int co = 0; co < 256; ++co) acc += lwT[co * 256 + d] * conv_b[co];
    b2[d] = acc;
}

// ---------------- |e_k|^2 ----------------
__global__ void embsq_k(const float* __restrict__ emb, float* __restrict__ esq) {
    int w = threadIdx.x >> 6, lane = threadIdx.x & 63;
    int k = blockIdx.x * 4 + w;
    const float* row = emb + (size_t)k * 256;
    float s = 0.f;
    #pragma unroll
    for (int i = 0; i < 4; ++i) { float v = row[lane + 64 * i]; s += v * v; }
    #pragma unroll
    for (int m = 32; m >= 1; m >>= 1) s += __shfl_xor(s, m, 64);
    if (lane == 0) esq[k] = s;
}

// ---------------- latent -> channel-last fp16 hi/lo: Xnp[(b*64+pix)*2+pl][512]
__global__ __launch_bounds__(256) void packlat_k(const float* __restrict__ lat,
                                                 _Float16* __restrict__ Xnp) {
    int b = blockIdx.x, t = threadIdx.x;
    __shared__ float lt[128][65];
    const float* src = lat + (size_t)b * 512 * 64;
    _Float16* dst = Xnp + (size_t)b * 64 * 1024;
    for (int c0 = 0; c0 < 512; c0 += 128) {
        __syncthreads();
        #pragma unroll
        for (int j = 0; j < 8; ++j) {
            int f4 = t + j * 256;                 // 0..2047
            int cc = f4 >> 4, p4 = (f4 & 15) * 4;
            float4 v = *(const float4*)(src + (size_t)(c0 + cc) * 64 + p4);
            lt[cc][p4] = v.x; lt[cc][p4 + 1] = v.y;
            lt[cc][p4 + 2] = v.z; lt[cc][p4 + 3] = v.w;
        }
        __syncthreads();
        int pix = t >> 2, cr = (t & 3) * 32;
        #pragma unroll
        for (int q = 0; q < 4; ++q) {
            half8_t hh, ll;
            #pragma unroll
            for (int j = 0; j < 8; ++j) {
                float v = lt[cr + q * 8 + j][pix];
                _Float16 h = (_Float16)v;
                hh[j] = h; ll[j] = (_Float16)(v - (float)h);
            }
            *(half8_t*)(dst + (size_t)pix * 1024 + c0 + cr + q * 8) = hh;
            *(half8_t*)(dst + (size_t)pix * 1024 + 512 + c0 + cr + q * 8) = ll;
        }
    }
}

// ---------------- conv as hi/lo fp16 MFMA GEMM ----------------
// grid (128 m-tiles, 2 n-tiles), 256 thr = 4 waves (2x2 of 64x64).
__global__ __launch_bounds__(256) void convm_k(
    const _Float16* __restrict__ Xnp, const _Float16* __restrict__ W2x,
    const float* __restrict__ b2, const _Float16* __restrict__ zp,
    float* __restrict__ yb) {
    int m0 = blockIdx.x * 128, n0 = blockIdx.y * 128;
    int tid = threadIdx.x, w = tid >> 6, lane = tid & 63;
    int wm = w & 1, wn = w >> 1;
    int fr = lane & 15, fq = lane >> 4;
    __shared__ _Float16 la[128 * 32];
    __shared__ _Float16 lb[128 * 32];
    f32x4 acc[4][4];
    #pragma unroll
    for (int s = 0; s < 4; ++s)
        #pragma unroll
        for (int t = 0; t < 4; ++t)
            #pragma unroll
            for (int r = 0; r < 4; ++r) acc[s][t][r] = 0.f;

    int s0 = w * 2048 + lane * 16;          // byte slot in 8KB tile
    int s1 = s0 + 1024;
    int row0 = s0 >> 6, ch0 = (s0 & 63) >> 1;
    int row1 = s1 >> 6, ch1 = (s1 & 63) >> 1;
    int b0_ = (m0 + row0) >> 6, i0 = (m0 + row0) & 63, h0 = i0 >> 3, x0 = i0 & 7;
    int b1_ = (m0 + row1) >> 6, i1 = (m0 + row1) & 63, h1 = i1 >> 3, x1 = i1 & 7;

    for (int seg = 0; seg < 3; ++seg) {
        int apl = (seg == 2) ? 1 : 0;
        int bpl = (seg == 1) ? 1 : 0;
        for (int tap = 0; tap < 9; ++tap) {
            int dy = tap / 3 - 1, dx = tap % 3 - 1;
            int ih0 = h0 + dy, iw0 = x0 + dx;
            int ih1 = h1 + dy, iw1 = x1 + dx;
            bool v0 = ((unsigned)ih0 < 8u) && ((unsigned)iw0 < 8u);
            bool v1 = ((unsigned)ih1 < 8u) && ((unsigned)iw1 < 8u);
            const _Float16* Ab0 = v0
                ? Xnp + (((size_t)(b0_ * 64 + ih0 * 8 + iw0) * 2 + apl) * 512 + ch0)
                : zp + ch0;
            const _Float16* Ab1 = v1
                ? Xnp + (((size_t)(b1_ * 64 + ih1 * 8 + iw1) * 2 + apl) * 512 + ch1)
                : zp + ch1;
            const _Float16* Bb0 =
                W2x + ((size_t)((bpl * 9 + tap) * 256 + n0 + row0) * 512 + ch0);
            const _Float16* Bb1 =
                W2x + ((size_t)((bpl * 9 + tap) * 256 + n0 + row1) * 512 + ch1);
            for (int c0 = 0; c0 < 512; c0 += 32) {
                __syncthreads();
                GLOAD_LDS16(Ab0 + c0, (char*)la + s0);
                GLOAD_LDS16(Ab1 + c0, (char*)la + s1);
                GLOAD_LDS16(Bb0 + c0, (char*)lb + s0);
                GLOAD_LDS16(Bb1 + c0, (char*)lb + s1);
                __syncthreads();
                half8_t af[4], bf[4];
                #pragma unroll
                for (int s = 0; s < 4; ++s)
                    af[s] = *(const half8_t*)&la[(wm * 64 + s * 16 + fr) * 32 + fq * 8];
                #pragma unroll
                for (int t = 0; t < 4; ++t)
                    bf[t] = *(const half8_t*)&lb[(wn * 64 + t * 16 + fr) * 32 + fq * 8];
                #pragma unroll
                for (int s = 0; s < 4; ++s)
                    #pragma unroll
                    for (int t = 0; t < 4; ++t)
                        acc[s][t] = __builtin_amdgcn_mfma_f32_16x16x32_f16(
                            af[s], bf[t], acc[s][t], 0, 0, 0);
            }
        }
    }
    float bv[4];
    #pragma unroll
    for (int t = 0; t < 4; ++t) bv[t] = b2[n0 + wn * 64 + t * 16 + fr];
    #pragma unroll
    for (int s = 0; s < 4; ++s)
        #pragma unroll
        for (int r = 0; r < 4; ++r) {
            int m = m0 + wm * 64 + s * 16 + fq * 4 + r;
            #pragma unroll
            for (int t = 0; t < 4; ++t) {
                int d = n0 + wn * 64 + t * 16 + fr;
                yb[(size_t)m * 256 + d] = acc[s][t][r] + bv[t];
            }
        }
}

// ---------------- fp32 -> fp16 hi pack ----------------
__global__ void packhi_k(const float* __restrict__ x, _Float16* __restrict__ o) {
    int i = blockIdx.x * 256 + threadIdx.x;
    float4 v = *(const float4*)(x + (size_t)i * 4);
    half4_t h = {(_Float16)v.x, (_Float16)v.y, (_Float16)v.z, (_Float16)v.w};
    *(half4_t*)(o + (size_t)i * 4) = h;
}

// ---------------- hi-only MFMA screen: K=256 ----------------
// grid (128 m-tiles, 64 n-tiles), 256 thr = 4 waves (2x2 of 64x64).
__global__ __launch_bounds__(256) void screen2_k(
    const _Float16* __restrict__ A2, const _Float16* __restrict__ B2,
    const float* __restrict__ esq, float* __restrict__ ps2, int* __restrict__ pi2) {
    int m0 = blockIdx.x * 128, n0 = blockIdx.y * 128;
    int tid = threadIdx.x, w = tid >> 6, lane = tid & 63;
    int wm = w & 1, wn = w >> 1;
    int fr = lane & 15, fq = lane >> 4;
    __shared__ _Float16 la[128 * 32];
    __shared__ _Float16 lb[128 * 32];
    f32x4 acc[4][4];
    #pragma unroll
    for (int s = 0; s < 4; ++s)
        #pragma unroll
        for (int t = 0; t < 4; ++t)
            #pragma unroll
            for (int r = 0; r < 4; ++r) acc[s][t][r] = 0.f;

    int s0 = w * 2048 + lane * 16;
    int s1 = s0 + 1024;
    int row0 = s0 >> 6, ch0 = (s0 & 63) >> 1;
    int row1 = s1 >> 6, ch1 = (s1 & 63) >> 1;
    const _Float16* Ab0 = A2 + ((size_t)(m0 + row0) * 256 + ch0);
    const _Float16* Ab1 = A2 + ((size_t)(m0 + row1) * 256 + ch1);
    const _Float16* Bb0 = B2 + ((size_t)(n0 + row0) * 256 + ch0);
    const _Float16* Bb1 = B2 + ((size_t)(n0 + row1) * 256 + ch1);

    for (int kt = 0; kt < 8; ++kt) {
        int ko = kt * 32;
        __syncthreads();
        GLOAD_LDS16(Ab0 + ko, (char*)la + s0);
        GLOAD_LDS16(Ab1 + ko, (char*)la + s1);
        GLOAD_LDS16(Bb0 + ko, (char*)lb + s0);
        GLOAD_LDS16(Bb1 + ko, (char*)lb + s1);
        __syncthreads();
        half8_t af[4], bf[4];
        #pragma unroll
        for (int s = 0; s < 4; ++s)
            af[s] = *(const half8_t*)&la[(wm * 64 + s * 16 + fr) * 32 + fq * 8];
        #pragma unroll
        for (int t = 0; t < 4; ++t)
            bf[t] = *(const half8_t*)&lb[(wn * 64 + t * 16 + fr) * 32 + fq * 8];
        #pragma unroll
        for (int s = 0; s < 4; ++s)
            #pragma unroll
            for (int t = 0; t < 4; ++t)
                acc[s][t] = __builtin_amdgcn_mfma_f32_16x16x32_f16(
                    af[s], bf[t], acc[s][t], 0, 0, 0);
    }

    float esv[4];
    #pragma unroll
    for (int t = 0; t < 4; ++t) esv[t] = esq[n0 + wn * 64 + t * 16 + fr];
    int colIdx = blockIdx.y * 2 + wn;
    #pragma unroll
    for (int s = 0; s < 4; ++s) {
        #pragma unroll
        for (int r = 0; r < 4; ++r) {
            float best = 3.4e38f; int bidx = 0x7fffffff;
            #pragma unroll
            for (int t = 0; t < 4; ++t) {
                float sc = esv[t] - 2.f * acc[s][t][r];
                int k = n0 + wn * 64 + t * 16 + fr;
                if (sc < best || (sc == best && k < bidx)) { best = sc; bidx = k; }
            }
            #pragma unroll
            for (int msk = 1; msk <= 8; msk <<= 1) {
                float so = __shfl_xor(best, msk, 64);
                int ko2 = __shfl_xor(bidx, msk, 64);
                if (so < best || (so == best && ko2 < bidx)) { best = so; bidx = ko2; }
            }
            if (fr == 0) {
                int m = m0 + wm * 64 + s * 16 + fq * 4 + r;
                ps2[(size_t)m * 128 + colIdx] = best;
                pi2[(size_t)m * 128 + colIdx] = bidx;
            }
        }
    }
}

// ---------------- exact fp32 refine over screen candidates ----------------
__global__ __launch_bounds__(256) void refine2_k(
    const float* __restrict__ y, const float* __restrict__ emb,
    const float* __restrict__ esq, const float* __restrict__ ps2,
    const int* __restrict__ pi2, int* __restrict__ out) {
    int lane = threadIdx.x & 63;
    int m = blockIdx.x * 4 + (threadIdx.x >> 6);
    float4 yv = *(const float4*)(y + (size_t)m * 256 + lane * 4);
    float sc_[2]; int kc_[2];
    #pragma unroll
    for (int i = 0; i < 2; ++i) {
        sc_[i] = ps2[(size_t)m * 128 + lane * 2 + i];
        kc_[i] = pi2[(size_t)m * 128 + lane * 2 + i];
    }
    float s0 = fminf(sc_[0], sc_[1]);
    #pragma unroll
    for (int msk = 1; msk <= 32; msk <<= 1) s0 = fminf(s0, __shfl_xor(s0, msk, 64));
    float thr = s0 + 0.25f;
    float best = 3.4e38f; int bk = 0x7fffffff;
    for (int c = 0; c < 128; ++c) {
        float scc = __shfl(sc_[c & 1], c >> 1, 64);
        if (scc <= thr) {            // wave-uniform
            int k = __shfl(kc_[c & 1], c >> 1, 64);
            float4 ev = *(const float4*)(emb + (size_t)k * 256 + lane * 4);
            float d = yv.x * ev.x + yv.y * ev.y + yv.z * ev.z + yv.w * ev.w;
            #pragma unroll
            for (int msk = 1; msk <= 32; msk <<= 1) d += __shfl_xor(d, msk, 64);
            float sx = esq[k] - 2.f * d;
            if (sx < best || (sx == best && k < bk)) { best = sx; bk = k; }
        }
    }
    if (lane == 0) out[m] = bk;
}

// ================= fallback: round-2 all-fp32 path =================
__global__ __launch_bounds__(256) void conv_k(
    const float* __restrict__ lat, const float* __restrict__ W2T,
    const float* __restrict__ b2, float* __restrict__ y) {
    int b = blockIdx.x;
    int tid = threadIdx.x;
    int dg = tid & 31, rg = tid >> 5;
    __shared__ float lw[36 * 256];
    __shared__ float at[36 * 72];
    float acc[8][8];
    #pragma unroll
    for (int j = 0; j < 8; ++j)
        #pragma unroll
        for (int i = 0; i < 8; ++i) acc[j][i] = 0.f;
    const float* latb = lat + (size_t)b * CIN_ * 64;
    for (int cc = 0; cc < 128; ++cc) {
        __syncthreads();
        const float4* wsrc = (const float4*)(W2T + (size_t)cc * 36 * 256);
        float4* wdst = (float4*)lw;
        #pragma unroll
        for (int i = 0; i < 9; ++i) wdst[tid + i * 256] = wsrc[tid + i * 256];
        #pragma unroll
        for (int i = 0; i < 9; ++i) {
            int n = tid + i * 256;
            int e = n >> 6, row = n & 63;
            int ci4 = (e * 456) >> 12;
            int t9 = e - ci4 * 9;
            int dy = (t9 * 342) >> 10;
            int dx = t9 - dy * 3;
            int hh = (row >> 3) + dy - 1, ww = (row & 7) + dx - 1;
            float v = 0.f;
            if (((unsigned)hh < 8u) && ((unsigned)ww < 8u))
                v = latb[(size_t)(cc * 4 + ci4) * 64 + hh * 8 + ww];
            at[e * 72 + row] = v;
        }
        __syncthreads();
        #pragma unroll 3
        for (int e4 = 0; e4 < 36; e4 += 4) {
            float4 a0[4], a1[4], w0[4], w1[4];
            #pragma unroll
            for (int q = 0; q < 4; ++q) {
                const float* ap = &at[(e4 + q) * 72 + rg * 8];
                a0[q] = *(const float4*)ap;
                a1[q] = *(const float4*)(ap + 4);
                const float* wp = &lw[(e4 + q) * 256 + dg * 4];
                w0[q] = *(const float4*)wp;
                w1[q] = *(const float4*)(wp + 128);
            }
            #pragma unroll
            for (int q = 0; q < 4; ++q) {
                float aj[8] = {a0[q].x, a0[q].y, a0[q].z, a0[q].w,
                               a1[q].x, a1[q].y, a1[q].z, a1[q].w};
                float wd[8] = {w0[q].x, w0[q].y, w0[q].z, w0[q].w,
                               w1[q].x, w1[q].y, w1[q].z, w1[q].w};
                #pragma unroll
                for (int j = 0; j < 8; ++j)
                    #pragma unroll
                    for (int i = 0; i < 8; ++i)
                        acc[j][i] += aj[j] * wd[i];
            }
        }
    }
    float4 bb0 = *(const float4*)(b2 + dg * 4);
    float4 bb1 = *(const float4*)(b2 + 128 + dg * 4);
    #pragma unroll
    for (int j = 0; j < 8; ++j) {
        int m = b * 64 + rg * 8 + j;
        float4 o0 = make_float4(acc[j][0] + bb0.x, acc[j][1] + bb0.y,
                                acc[j][2] + bb0.z, acc[j][3] + bb0.w);
        float4 o1 = make_float4(acc[j][4] + bb1.x, acc[j][5] + bb1.y,
                                acc[j][6] + bb1.z, acc[j][7] + bb1.w);
        *(float4*)(y + (size_t)m * 256 + dg * 4) = o0;
        *(float4*)(y + (size_t)m * 256 + 128 + dg * 4) = o1;
    }
}

__global__ __launch_bounds__(256) void dist_k(
    const float* __restrict__ y, const float* __restrict__ emb,
    const float* __restrict__ esq, float* __restrict__ ps, int* __restrict__ pi) {
    int ct = blockIdx.x, rt = blockIdx.y;
    int k0 = ct * 256, m0 = rt * 64;
    int cg = threadIdx.x & 31, rg = threadIdx.x >> 5;
    __shared__ float ylds[64][32];
    __shared__ float et[32][260];
    float acc[8][8];
    #pragma unroll
    for (int j = 0; j < 8; ++j)
        #pragma unroll
        for (int i = 0; i < 8; ++i) acc[j][i] = 0.f;
    for (int c0 = 0; c0 < 256; c0 += 32) {
        __syncthreads();
        #pragma unroll
        for (int i = 0; i < 2; ++i) {
            int f = i * 1024 + threadIdx.x * 4;
            int row = f >> 5, c = f & 31;
            *(float4*)&ylds[row][c] =
                *(const float4*)(y + (size_t)(m0 + row) * 256 + c0 + c);
        }
        {
            int kk = threadIdx.x;
            const float* er = emb + (size_t)(k0 + kk) * 256 + c0;
            #pragma unroll
            for (int q = 0; q < 8; ++q) {
                float4 v = ((const float4*)er)[q];
                et[q * 4 + 0][kk] = v.x; et[q * 4 + 1][kk] = v.y;
                et[q * 4 + 2][kk] = v.z; et[q * 4 + 3][kk] = v.w;
            }
        }
        __syncthreads();
        #pragma unroll
        for (int c4 = 0; c4 < 32; c4 += 4) {
            float4 e0[4], e1[4];
            #pragma unroll
            for (int q = 0; q < 4; ++q) {
                e0[q] = *(const float4*)&et[c4 + q][cg * 4];
                e1[q] = *(const float4*)&et[c4 + q][128 + cg * 4];
            }
            #pragma unroll
            for (int j = 0; j < 8; ++j) {
                float4 yv = *(const float4*)&ylds[rg * 8 + j][c4];
                float ya[4] = {yv.x, yv.y, yv.z, yv.w};
                #pragma unroll
                for (int q = 0; q < 4; ++q) {
                    acc[j][0] += ya[q] * e0[q].x; acc[j][1] += ya[q] * e0[q].y;
                    acc[j][2] += ya[q] * e0[q].z; acc[j][3] += ya[q] * e0[q].w;
                    acc[j][4] += ya[q] * e1[q].x; acc[j][5] += ya[q] * e1[q].y;
                    acc[j][6] += ya[q] * e1[q].z; acc[j][7] += ya[q] * e1[q].w;
                }
            }
        }
    }
    float4 q0 = *(const float4*)(esq + k0 + cg * 4);
    float4 q1 = *(const float4*)(esq + k0 + 128 + cg * 4);
    float es[8] = {q0.x, q0.y, q0.z, q0.w, q1.x, q1.y, q1.z, q1.w};
    #pragma unroll
    for (int j = 0; j < 8; ++j) {
        float best = 3.4e38f; int bidx = 0;
        #pragma unroll
        for (int i = 0; i < 8; ++i) {
            float s = es[i] - 2.f * acc[j][i];
            int k = (i < 4) ? (k0 + 4 * cg + i) : (k0 + 128 + 4 * cg + (i - 4));
            if (s < best) { best = s; bidx = k; }
        }
        #pragma unroll
        for (int mask = 1; mask <= 16; mask <<= 1) {
            float so = __shfl_xor(best, mask, 64);
            int ko = __shfl_xor(bidx, mask, 64);
            if (so < best || (so == best && ko < bidx)) { best = so; bidx = ko; }
        }
        if (cg == 0) {
            int m = m0 + rg * 8 + j;
            ps[(size_t)m * 32 + ct] = best;
            pi[(size_t)m * 32 + ct] = bidx;
        }
    }
}

__global__ void final_k(const float* __restrict__ ps, const int* __restrict__ pi,
                        int* __restrict__ out) {
    int m = blockIdx.x * 256 + threadIdx.x;
    float bs = 3.4e38f; int bk = 0;
    for (int t = 0; t < 32; ++t) {
        float s = ps[(size_t)m * 32 + t];
        int k = pi[(size_t)m * 32 + t];
        if (s < bs) { bs = s; bk = k; }
    }
    out[m] = bk;
}

extern "C" void kernel_launch(void* const* d_in, const int* in_sizes, int n_in,
                              void* d_out, int out_size, void* d_ws, size_t ws_size,
                              hipStream_t stream) {
    const float* latent = (const float*)d_in[0];
    const float* conv_w = (const float*)d_in[1];
    const float* conv_b = (const float*)d_in[2];
    const float* lin_w  = (const float*)d_in[3];
    const float* lin_b  = (const float*)d_in[4];
    const float* emb    = (const float*)d_in[5];
    int* out = (int*)d_out;

    char* W = (char*)d_ws;
    float*    lwT = (float*)(W + 0);                 //   262,144 B
    float*    b2  = (float*)(W + 262144);            //     1,024 B
    float*    esq = (float*)(W + 263168);            //    32,768 B
    float*    yb  = (float*)(W + 295936);            // 16,777,216 B
    _Float16* W2x = (_Float16*)(W + 17073152);       //  4,718,592 B
    _Float16* zp  = (_Float16*)(W + 21791744);       //     1,024 B
    _Float16* Xnp = (_Float16*)(W + 21792768);       // 33,554,432 B -> end 55,347,200
    // alias region on Xnp (dead after convm_k):
    _Float16* A2  = (_Float16*)(W + 21792768);       //  8,388,608 B
    _Float16* B2  = (_Float16*)(W + 30181376);       //  4,194,304 B
    float*    ps2 = (float*)(W + 34375680);          //  8,388,608 B
    int*      pi2 = (int*)(W + 42764288);            //  8,388,608 B -> 51,152,896 <= 55,347,200
    size_t need_fast = 55347200;

    dim3 t32(32, 32);
    tkern<<<dim3(8, 8), t32, 0, stream>>>(lin_w, lwT, 256, 256);
    bias_k<<<1, 256, 0, stream>>>(lwT, conv_b, lin_b, b2);
    embsq_k<<<2048, 256, 0, stream>>>(emb, esq);

    if (ws_size >= need_fast) {
        fold3_k<<<E_, 256, 0, stream>>>(conv_w, lwT, W2x);
        hipMemsetAsync(zp, 0, 1024, stream);
        packlat_k<<<256, 256, 0, stream>>>(latent, Xnp);
        convm_k<<<dim3(128, 2), 256, 0, stream>>>(Xnp, W2x, b2, zp, yb);
        packhi_k<<<4096, 256, 0, stream>>>(yb, A2);     // 16384x256
        packhi_k<<<2048, 256, 0, stream>>>(emb, B2);    // 8192x256
        screen2_k<<<dim3(128, 64), 256, 0, stream>>>(A2, B2, esq, ps2, pi2);
        refine2_k<<<4096, 256, 0, stream>>>(yb, emb, esq, ps2, pi2, out);
    } else {
        // fp32 fallback (round-2 path)
        float* W2T = (float*)(W + 17073152);            // 4,718,592 B
        float* ps  = (float*)(W + 21791744);            // 2,097,152 B
        int*   pi  = (int*)(W + 23888896);              // 2,097,152 B
        fold2_k<<<E_, 256, 0, stream>>>(conv_w, lwT, W2T);
        conv_k<<<256, 256, 0, stream>>>(latent, W2T, b2, yb);
        dist_k<<<dim3(32, 256), 256, 0, stream>>>(yb, emb, esq, ps, pi);
        final_k<<<64, 256, 0, stream>>>(ps, pi, out);
    }
}